// Round 3
// baseline (177.994 us; speedup 1.0000x reference)
//
#include <hip/hip_runtime.h>

// CostConcatenation: out[b, dd, h, w, :] = valid ? concat(left[b,h,w,:], right[b,h,w-d,:]) : 0
//   d = dd - 48, valid iff 0 <= w-d < 256 (both halves zeroed when invalid).
// Shapes: left/right [2,64,256,32] f32; out [2,96,64,256,64] f32 (805 MB).
// Pure streaming-write kernel; roofline = HBM write BW (~6.5 TB/s memset rate -> ~120us).
//
// Structure: each thread owns (b, h, w, side, c3) and loops over all 96 disparities.
//   - side (left/right half of channel concat) sits at bit 11 of tid -> wave-uniform,
//     so left waves store a hoisted register constant and right waves do a pure
//     load+store with a linearly-decrementing address. No intra-wave divergence.
//   - valid dd range [dd_lo, dd_hi] computed once; zero-fill loops outside it have
//     no loads and no selects.
//   - nontemporal stores keep the 805 MB stream out of L2 (which serves right reads).
//
// NOTE: __builtin_nontemporal_store requires a NATIVE clang vector type, not
// HIP's float4 class -> use ext_vector_type(4).

typedef float f4 __attribute__((ext_vector_type(4)));

#define DD_STRIDE 262144   // 64*256*16 float4 between consecutive disparity slices

__global__ __launch_bounds__(256) void cost_concat_kernel(
    const f4* __restrict__ left4,
    const f4* __restrict__ right4,
    f4* __restrict__ out4)
{
    const int tid = blockIdx.x * 256 + threadIdx.x;  // 0..524287, one thread per (b,h,w,side,c3)
    const int c3 = tid & 7;            // which float4 within the 32-channel half
    const int w  = (tid >> 3) & 255;
    const int s  = (tid >> 11) & 1;    // 0 = left half, 1 = right half (wave-uniform)
    const int hb = tid >> 12;          // b*64 + h
    const int b  = hb >> 6;
    const int h  = hb & 63;

    const int rowBase = hb * 2048;     // float4 index of input row (b,h,:,:)  (256*8)

    // out float4 index of (b, dd=0, h, w, s, c3); dd stride = DD_STRIDE
    f4* optr = out4 + (size_t)b * 25165824 + (size_t)h * 4096
                    + (size_t)(w * 16 + s * 8 + c3);

    // valid iff 0 <= w - (dd-48) < 256  ->  dd in [w-207, w+48]
    const int dd_lo = max(0, w - 207);
    const int dd_hi = min(95, w + 48);   // inclusive
    const f4 z = (f4){0.f, 0.f, 0.f, 0.f};

    int dd = 0;
    for (; dd < dd_lo; ++dd)
        __builtin_nontemporal_store(z, optr + (size_t)dd * DD_STRIDE);

    if (s == 0) {
        const f4 v = left4[rowBase + w * 8 + c3];
        #pragma unroll 4
        for (; dd <= dd_hi; ++dd)
            __builtin_nontemporal_store(v, optr + (size_t)dd * DD_STRIDE);
    } else {
        const f4* rp = right4 + rowBase + (w + 48) * 8 + c3;  // idx = w+48-dd
        #pragma unroll 4
        for (; dd <= dd_hi; ++dd)
            __builtin_nontemporal_store(rp[-(ptrdiff_t)dd * 8], optr + (size_t)dd * DD_STRIDE);
    }

    for (; dd < 96; ++dd)
        __builtin_nontemporal_store(z, optr + (size_t)dd * DD_STRIDE);
}

extern "C" void kernel_launch(void* const* d_in, const int* in_sizes, int n_in,
                              void* d_out, int out_size, void* d_ws, size_t ws_size,
                              hipStream_t stream) {
    const f4* left4  = (const f4*)d_in[0];
    const f4* right4 = (const f4*)d_in[1];
    f4* out4 = (f4*)d_out;

    // 524288 threads exactly cover (b,h,w,side,c3); 2048 blocks = 8 blocks/CU.
    cost_concat_kernel<<<2048, 256, 0, stream>>>(left4, right4, out4);
}

// Round 4
// 149.116 us; speedup vs baseline: 1.1937x; 1.1937x over previous
//
#include <hip/hip_runtime.h>

// CostConcatenation: out[b, dd, h, w, :] = valid ? concat(left[b,h,w,:], right[b,h,w-d,:]) : 0
//   d = dd - 48, valid iff 0 <= w-d < 256 (both halves zeroed when invalid).
// Shapes: left/right [2,64,256,32] f32; out [2,96,64,256,64] f32 (805 MB written once).
//
// R3 theory: R0/R1 ran at 4.7 TB/s vs 6.8 TB/s for the harness's pure-store fill.
// Difference = the global read stream (8 MB inputs re-read 96x miss L2 under write
// pressure -> L3/HBM reads + load latency coupled into every store). Fix: stage the
// (b,h) row of left+right into LDS once per block; hot loop = ds_read_b128 (bank-
// conflict-free) + contiguous 1KB/wave stores. Global reads: 32 MB one-time total.
//
// Block = (b, h, dd_group): 2*64*4 = 512 blocks x 256 thr; 64 KB LDS -> 2 blocks/CU.

typedef float f4 __attribute__((ext_vector_type(4)));

#define DD_STRIDE 262144   // f4 per disparity slice (64*256*16)

__global__ __launch_bounds__(256) void cost_concat_kernel(
    const f4* __restrict__ left4,
    const f4* __restrict__ right4,
    f4* __restrict__ out4)
{
    __shared__ f4 lds[4096];           // [0,2048) = left row, [2048,4096) = right row

    const int t   = threadIdx.x;
    const int blk = blockIdx.x;        // 0..511
    const int g   = blk & 3;           // dd group: dd in [g*24, g*24+24)
    const int hb  = blk >> 2;          // b*64 + h
    const int rowBase = hb * 2048;     // f4 index of input row (256 w * 8 f4)

    // Stage left + right rows (fully coalesced, one-time).
    #pragma unroll
    for (int k = 0; k < 8; ++k)
        lds[k * 256 + t] = left4[rowBase + k * 256 + t];
    #pragma unroll
    for (int k = 0; k < 8; ++k)
        lds[2048 + k * 256 + t] = right4[rowBase + k * 256 + t];
    __syncthreads();

    const int c4  = t & 15;            // float4 within the 64-channel pixel
    const int wb  = t >> 4;            // w low bits (0..15)
    const bool isLeft = c4 < 8;
    const int cc  = c4 & 7;
    const int b   = hb >> 6;
    const int h   = hb & 63;
    const int dd0 = g * 24;

    // out f4 base of (b, dd0, h, 0, 0): row is 4096 f4, written as 24 slices.
    f4* orow = out4 + (size_t)b * 25165824 + (size_t)dd0 * DD_STRIDE + (size_t)h * 4096;

    for (int k = 0; k < 24; ++k) {     // disparity within group
        const int d = dd0 + k - 48;
        f4* op = orow + (size_t)k * DD_STRIDE + t;
        #pragma unroll
        for (int j = 0; j < 16; ++j) { // 16 x 1KB contiguous wave stores cover the slice row
            const int w   = j * 16 + wb;
            const int idx = w - d;                      // right-image column
            const bool valid = (unsigned)idx < 256u;
            const int ci  = valid ? idx : 0;            // masked anyway; keep LDS addr in range
            const int la  = isLeft ? (w * 8 + cc) : (2048 + ci * 8 + cc);
            f4 v = lds[la];
            v = valid ? v : (f4){0.f, 0.f, 0.f, 0.f};
            op[j * 256] = v;
        }
    }
}

extern "C" void kernel_launch(void* const* d_in, const int* in_sizes, int n_in,
                              void* d_out, int out_size, void* d_ws, size_t ws_size,
                              hipStream_t stream) {
    const f4* left4  = (const f4*)d_in[0];
    const f4* right4 = (const f4*)d_in[1];
    f4* out4 = (f4*)d_out;

    cost_concat_kernel<<<512, 256, 0, stream>>>(left4, right4, out4);
}